// Round 7
// baseline (634.514 us; speedup 1.0000x reference)
//
#include <hip/hip_runtime.h>

#define DEVI __device__ __forceinline__

constexpr float SCALE = 0.0625f;   // 256^-0.5
constexpr float LN_EPS = 1e-5f;
#define NBSLOT 128u

// ---------------- grid barrier (device-scope, monotonic counter) ----------------
DEVI void grid_barrier(unsigned* bar, unsigned target){
  __syncthreads();
  if (threadIdx.x == 0){
    __threadfence();   // flush my XCD L2 to device coherence point
    __hip_atomic_fetch_add(bar, 1u, __ATOMIC_ACQ_REL, __HIP_MEMORY_SCOPE_AGENT);
    while (__hip_atomic_load(bar, __ATOMIC_ACQUIRE, __HIP_MEMORY_SCOPE_AGENT) < target){
      __builtin_amdgcn_s_sleep(2);
    }
    __threadfence();   // invalidate stale lines before post-barrier reads
  }
  __syncthreads();
}

// stage 8 rows (rb + j*8, j=0..7) of a [*,256] fp32 matrix into xs[8*256]
DEVI void stage8(float* xs, const float* __restrict__ src, int rb, int tid){
  int j = tid >> 7, k = (tid & 127) * 2;
  *(float2*)(xs + j*256 + k) = *(const float2*)(src + (size_t)(rb + j*8)*256 + k);
}

// 8x32-out GEMM tile vs row-major W[out][256]: thread (out=tid>>2: j=out>>5,
// c=out&31; ks=tid&3) accumulates k-chunk ks*64..+64 (bank-rotated), then
// butterfly over ks. Returns the full dot in ALL 4 lanes of the quad.
DEVI float tile_gemm(const float* __restrict__ W, int c0, const float* xs, int tid){
  const int out = tid >> 2, ks = tid & 3;
  const int j = out >> 5, c = out & 31;
  const float* wrow = W + (size_t)(c0 + c) * 256;
  float acc = 0.f;
  #pragma unroll
  for (int i4 = 0; i4 < 16; ++i4){
    int kk = ks*64 + ((i4 + 2*ks) & 15)*4;
    float4 w = *(const float4*)(wrow + kk);
    float4 x = *(const float4*)(xs + j*256 + kk);
    acc += w.x*x.x + w.y*x.y + w.z*x.z + w.w*x.w;
  }
  acc += __shfl_xor(acc, 1, 64);
  acc += __shfl_xor(acc, 2, 64);
  return acc;
}

// qk tile: out[j][c] = sum_e xs[j][e] * Wks[e][c0+c]  (k-dim strided in W)
DEVI float tile_outer_qk(const float* __restrict__ Wks, int c0, const float* xs, int tid){
  const int out = tid >> 2, ks = tid & 3;
  const int j = out >> 5, c = out & 31;
  float acc = 0.f;
  #pragma unroll 8
  for (int i = 0; i < 64; ++i){
    int e = ks*64 + ((i + 8*ks) & 63);
    acc += xs[j*256 + e] * Wks[(size_t)e*256 + c0 + c];
  }
  acc += __shfl_xor(acc, 1, 64);
  acc += __shfl_xor(acc, 2, 64);
  return acc;
}

// in-place LN of the 8 staged rows (entered unsynced after staging)
DEVI void ln_rows(float* xs, const float* __restrict__ g, const float* __restrict__ be,
                  float* muL, float* invL, int tid){
  __syncthreads();
  if (tid < 512){
    int j = tid >> 6, l = tid & 63;
    float s1 = 0.f, s2 = 0.f;
    #pragma unroll
    for (int q = 0; q < 4; ++q){ float v = xs[j*256 + q*64 + l]; s1 += v; s2 += v*v; }
    #pragma unroll
    for (int o = 32; o; o >>= 1){ s1 += __shfl_xor(s1,o,64); s2 += __shfl_xor(s2,o,64); }
    if (l == 0){
      float mu = s1*(1.f/256.f);
      float var = s2*(1.f/256.f) - mu*mu;
      muL[j] = mu; invL[j] = rsqrtf(var + LN_EPS);
    }
  }
  __syncthreads();
  {
    int j = tid >> 7, k = (tid & 127)*2;
    float mu = muL[j], inv = invL[j];
    float2 v = *(float2*)(xs + j*256 + k);
    v.x = (v.x - mu)*inv*g[k]   + be[k];
    v.y = (v.y - mu)*inv*g[k+1] + be[k+1];
    *(float2*)(xs + j*256 + k) = v;
  }
  __syncthreads();
}

// ---------------- K0: slots init + zero accumulators/barrier ----------------
__global__ void k_init(const float* __restrict__ noise, const float* __restrict__ smu,
                       const float* __restrict__ slsig, float* __restrict__ slotsA,
                       float* __restrict__ uacc, float* __restrict__ Zacc,
                       unsigned* __restrict__ bar){
  const int r = blockIdx.x, tid = threadIdx.x, s = r & 7;
  slotsA[r*256 + tid] = smu[s*256 + tid] + expf(slsig[s*256 + tid]) * noise[r*256 + tid];
  uacc[r*256 + tid] = 0.f;
  if (tid == 0) Zacc[r] = 0.f;
  if (r == 0 && tid == 0) bar[0] = 0u;
}

// ---------------- K2: persistent slot-side chain with grid barriers ----------------
// 128 blocks x 1024 thr. block = (rg = bIdx>>3, cg = bIdx&7): s = rg&7,
// bh = rg>>3, rows r(j) = bh*64 + j*8 + s (j=0..7), out-cols [cg*32, +32).
__global__ __launch_bounds__(1024, 4) void k_slot(
    const float* __restrict__ slots_in, float* __restrict__ slots_out,
    float* __restrict__ uacc, float* __restrict__ Zacc,
    const float* __restrict__ Wv,
    const float* __restrict__ W_ih, const float* __restrict__ W_hh,
    const float* __restrict__ b_ih, const float* __restrict__ b_hh,
    const float* __restrict__ W1, const float* __restrict__ b1,
    const float* __restrict__ W2, const float* __restrict__ b2,
    const float* __restrict__ g_ff, const float* __restrict__ be_ff,
    const float* __restrict__ Wq, const float* __restrict__ Wk,
    const float* __restrict__ g_s, const float* __restrict__ be_s,
    const float* __restrict__ g_in, const float* __restrict__ be_in,
    float* __restrict__ qg, float* __restrict__ gqbq,
    float* __restrict__ upd, float* __restrict__ gh,
    float* __restrict__ hbuf, float* __restrict__ hid, float* __restrict__ qbuf,
    unsigned* __restrict__ bar, unsigned bar_base,
    float* __restrict__ out_slots, int last, int initmode){
  __shared__ float xs[8*256];
  __shared__ float rzL[8], muL[8], invL[8];
  const int tid = threadIdx.x;
  const int rg = blockIdx.x >> 3, cg = blockIdx.x & 7;
  const int s = rg & 7, bh = rg >> 3, c0 = cg*32;
  const int rb = bh*64 + s;                 // row base (stride 8 in j)
  const int out = tid >> 2, j_o = out >> 5, c_o = out & 31;
  const int r_o = rb + j_o*8;               // my output row
  const bool own = (tid & 3) == 0;
  unsigned bno = 0;

  if (!initmode){
    // ---- S1: upd = (uacc @ Wv[s]^T) * rz ; gh_{r,z,n} = slots_in @ W_hh^T
    stage8(xs, uacc, rb, tid);
    if (tid < 8) rzL[tid] = 1.f / Zacc[rb + tid*8];
    __syncthreads();
    {
      float v = tile_gemm(Wv + (size_t)s*65536, c0, xs, tid);
      if (own) upd[r_o*256 + c0 + c_o] = v * rzL[j_o];
    }
    __syncthreads();
    stage8(xs, slots_in, rb, tid);
    __syncthreads();
    {
      float v0 = tile_gemm(W_hh,          c0, xs, tid);
      float v1 = tile_gemm(W_hh +  65536, c0, xs, tid);
      float v2 = tile_gemm(W_hh + 131072, c0, xs, tid);
      if (own){
        gh[(0*128 + r_o)*256 + c0 + c_o] = v0;
        gh[(1*128 + r_o)*256 + c0 + c_o] = v1;
        gh[(2*128 + r_o)*256 + c0 + c_o] = v2;
      }
    }
    grid_barrier(bar, bar_base + (++bno)*NBSLOT);

    // ---- S2: gi = upd @ W_ih^T ; h = GRU gates ; zero uacc/Zacc for next iter
    stage8(xs, upd, rb, tid);
    __syncthreads();
    {
      float i0 = tile_gemm(W_ih,          c0, xs, tid);
      float i1 = tile_gemm(W_ih +  65536, c0, xs, tid);
      float i2 = tile_gemm(W_ih + 131072, c0, xs, tid);
      if (own){
        int cc = c0 + c_o;
        float h_r = gh[(0*128 + r_o)*256 + cc] + b_hh[cc];
        float h_z = gh[(1*128 + r_o)*256 + cc] + b_hh[256 + cc];
        float h_n = gh[(2*128 + r_o)*256 + cc] + b_hh[512 + cc];
        float i_r = i0 + b_ih[cc];
        float i_z = i1 + b_ih[256 + cc];
        float i_n = i2 + b_ih[512 + cc];
        float hp = slots_in[r_o*256 + cc];
        float rg_ = 1.f/(1.f + expf(-(i_r + h_r)));
        float zg_ = 1.f/(1.f + expf(-(i_z + h_z)));
        float ng_ = tanhf(i_n + rg_*h_n);
        hbuf[r_o*256 + cc] = (1.f - zg_)*ng_ + zg_*hp;
      }
    }
    if (tid < 256){ int jj = tid >> 5, cc = tid & 31;
      uacc[(rb + jj*8)*256 + c0 + cc] = 0.f; }
    if (cg == 0 && tid < 8) Zacc[rb + tid*8] = 0.f;
    grid_barrier(bar, bar_base + (++bno)*NBSLOT);

    // ---- S3: hid = relu(LN_ff(h) @ W1^T + b1)
    stage8(xs, hbuf, rb, tid);
    ln_rows(xs, g_ff, be_ff, muL, invL, tid);
    {
      float v = tile_gemm(W1, c0, xs, tid);
      if (own) hid[r_o*256 + c0 + c_o] = fmaxf(v + b1[c0 + c_o], 0.f);
    }
    grid_barrier(bar, bar_base + (++bno)*NBSLOT);

    // ---- S4: slots_out = h + hid @ W2^T + b2
    stage8(xs, hid, rb, tid);
    __syncthreads();
    {
      float v = tile_gemm(W2, c0, xs, tid);
      if (own){
        int cc = c0 + c_o;
        float o = hbuf[r_o*256 + cc] + v + b2[cc];
        slots_out[r_o*256 + cc] = o;
        if (last) out_slots[r_o*256 + cc] = o;
      }
    }
    if (last) return;
    grid_barrier(bar, bar_base + (++bno)*NBSLOT);
  }

  // ---- S5: q = LN_s(slots_out) @ Wq^T ; zero gqbq
  stage8(xs, slots_out, rb, tid);
  ln_rows(xs, g_s, be_s, muL, invL, tid);
  {
    float v = tile_gemm(Wq, c0, xs, tid);
    if (own) qbuf[r_o*256 + c0 + c_o] = v;
  }
  if (cg == 0 && tid < 16) gqbq[(rb + (tid>>1)*8)*2 + (tid & 1)] = 0.f;
  grid_barrier(bar, bar_base + (++bno)*NBSLOT);

  // ---- S6: qk = q @ Wk[s] ; qg = qk*g_in*SCALE ; Gq/Bq row-sums (atomic)
  stage8(xs, qbuf, rb, tid);
  __syncthreads();
  {
    float qk = tile_outer_qk(Wk + (size_t)s*65536, c0, xs, tid);
    int cc = c0 + c_o;
    float qgv = qk * g_in[cc] * SCALE;
    float bqv = qk * be_in[cc] * SCALE;
    if (own) qg[r_o*256 + cc] = qgv;
    float vq = own ? qgv : 0.f, vb = own ? bqv : 0.f;
    #pragma unroll
    for (int o = 32; o; o >>= 1){ vq += __shfl_xor(vq,o,64); vb += __shfl_xor(vb,o,64); }
    if ((tid & 63) == 0){
      atomicAdd(&gqbq[r_o*2 + 0], vq);
      atomicAdd(&gqbq[r_o*2 + 1], vb);
    }
  }
}

// ---------------- K1: fused LN + dots + softmax(slots) + weighted-emb accumulation --------
// one block = 64-token tile. Phase 1 streams emb (fused LN+dots); phase 2
// coalesced f4 accumulation. Sp4 (32 KB) overlays phase-1's qgL/avL (LDS union).
__global__ __launch_bounds__(256) void k_main(const float* __restrict__ emb,
    const float* __restrict__ qg, const float* __restrict__ gqbq,
    const float* __restrict__ g_in, const float* __restrict__ be_in,
    float* __restrict__ uacc, float* __restrict__ Zacc,
    float* __restrict__ out_attn, int write_attn){
  __shared__ float U[8192];                    // 32 KB union
  float* const qgL = U;                        // [2048] phase 1 (bank-swizzled)
  float* const avL = U + 2048;                 // [512]  phase 1
  float4* const Sp4 = (float4*)U;              // [2048] phase 2 partials
  __shared__ float aL[512];
  __shared__ float red2[2][8][4];
  __shared__ float Zs[8], A2s[8], GqL[8], BqL[8];

  const int tid = threadIdx.x, lane = tid & 63, wv = tid >> 6;
  const int blk = blockIdx.x, b = blk >> 6, tile = blk & 63;
  const int n0 = tile * 64;

  { // stage queries with per-qq rotation so the 8 qq-chunks hit distinct banks
    const float4* src = (const float4*)(qg + (size_t)b * 2048);
    float4* dst = (float4*)qgL;
    #pragma unroll
    for (int k = 0; k < 2; ++k){
      int w = tid + k*256;                 // 0..511
      int s = w >> 6, f = w & 63, qq = f >> 3, j = f & 7;
      dst[s*64 + qq*8 + ((j + qq) & 7)] = src[w];
    }
  }
  if (tid < 8){
    GqL[tid] = gqbq[(b*8 + tid)*2 + 0];
    BqL[tid] = gqbq[(b*8 + tid)*2 + 1];
  }
  __syncthreads();

  const int qq = tid & 7;   // 32-col chunk
  float zsum[8], z2sum[8];
  #pragma unroll
  for (int s = 0; s < 8; ++s){ zsum[s] = 0.f; z2sum[s] = 0.f; }

  #pragma unroll
  for (int pass = 0; pass < 2; ++pass){
    const int t = pass*32 + (tid >> 3);   // token 0..63
    const float4* xrow = (const float4*)(emb + ((size_t)(b*4096 + n0 + t))*256 + qq*32);
    float4 xv4[8];
    #pragma unroll
    for (int j = 0; j < 8; ++j) xv4[j] = xrow[j];
    float s1 = 0.f, s2 = 0.f, acc[8];
    #pragma unroll
    for (int s = 0; s < 8; ++s) acc[s] = 0.f;
    #pragma unroll
    for (int j = 0; j < 8; ++j){
      float4 u = xv4[j];
      s1 += (u.x+u.y)+(u.z+u.w);
      s2 += u.x*u.x+u.y*u.y+u.z*u.z+u.w*u.w;
      const float* qb = qgL + qq*32 + ((j + qq) & 7)*4;
      #pragma unroll
      for (int s = 0; s < 8; ++s){
        float4 q0 = *(const float4*)(qb + s*256);
        acc[s] += u.x*q0.x + u.y*q0.y + u.z*q0.z + u.w*q0.w;
      }
    }
    #pragma unroll
    for (int o = 1; o <= 4; o <<= 1){
      s1 += __shfl_xor(s1,o,64); s2 += __shfl_xor(s2,o,64);
      #pragma unroll
      for (int s = 0; s < 8; ++s) acc[s] += __shfl_xor(acc[s],o,64);
    }
    float mu = s1 * (1.f/256.f);
    float var = s2 * (1.f/256.f) - mu*mu;
    float inv = rsqrtf(var + LN_EPS);
    float dv[8], mx = -1e30f;
    #pragma unroll
    for (int s = 0; s < 8; ++s){
      dv[s] = inv * (acc[s] - mu * GqL[s]) + BqL[s];
      mx = fmaxf(mx, dv[s]);
    }
    float den = 0.f;
    #pragma unroll
    for (int s = 0; s < 8; ++s){ dv[s] = expf(dv[s] - mx); den += dv[s]; }
    float rden = 1.f / den;
    #pragma unroll
    for (int s = 0; s < 8; ++s){
      float at = dv[s] * rden;       // attn (softmax over slots)
      float av = at * inv;           // attn * inv (LN folded)
      if (qq == 0){ avL[s*64 + t] = at; aL[s*64 + t] = av; }
      float z1 = at, z2 = av * mu;
      #pragma unroll
      for (int o = 32; o; o >>= 1){ z1 += __shfl_xor(z1, o, 64); z2 += __shfl_xor(z2, o, 64); }
      zsum[s] += z1 * 0.125f;        // 8 lanes per token
      z2sum[s] += z2 * 0.125f;
    }
  }
  if (lane == 0){
    #pragma unroll
    for (int s = 0; s < 8; ++s){ red2[0][s][wv] = zsum[s]; red2[1][s][wv] = z2sum[s]; }
  }
  __syncthreads();
  if (tid < 8){
    Zs[tid]  = red2[0][tid][0]+red2[0][tid][1]+red2[0][tid][2]+red2[0][tid][3];
    A2s[tid] = red2[1][tid][0]+red2[1][tid][1]+red2[1][tid][2]+red2[1][tid][3];
  }
  if (write_attn){
    int s = tid >> 5, tk = tid & 31;
    #pragma unroll
    for (int p = 0; p < 2; ++p)
      out_attn[((size_t)(b*8 + s))*4096 + n0 + p*32 + tk] = avL[s*64 + p*32 + tk];
  }
  __syncthreads();                   // avL/qgL dead past here; Sp4 takes over U
  { // phase 2: coalesced f4 token-weighted accumulation
    const int r4 = tid >> 6, cq = tid & 63;
    float4 S1[8];
    #pragma unroll
    for (int s = 0; s < 8; ++s) S1[s] = make_float4(0.f,0.f,0.f,0.f);
    const float4* xbase = (const float4*)(emb + ((size_t)(b*4096 + n0))*256) + cq;
    #pragma unroll 4
    for (int i = 0; i < 16; ++i){
      int t = r4 + i*4;
      float4 x4 = xbase[t*64];
      #pragma unroll
      for (int s = 0; s < 8; ++s){
        float a = aL[s*64 + t];   // wave-uniform broadcast
        S1[s].x += a*x4.x; S1[s].y += a*x4.y; S1[s].z += a*x4.z; S1[s].w += a*x4.w;
      }
    }
    #pragma unroll
    for (int s = 0; s < 8; ++s) Sp4[(r4*8 + s)*64 + cq] = S1[s];
  }
  __syncthreads();
  { // final: sum 4 wave-partials per (s,c), atomically accumulate (s staggered)
    const int c = tid;
    const float* Sp = (const float*)Sp4;
    float gc = g_in[c], bc = be_in[c];
    float* dst = uacc + ((size_t)b*8)*256 + c;
    #pragma unroll
    for (int si = 0; si < 8; ++si){
      int s = (si + blk) & 7;
      float v = Sp[(0*8+s)*256 + c] + Sp[(1*8+s)*256 + c]
              + Sp[(2*8+s)*256 + c] + Sp[(3*8+s)*256 + c];
      atomicAdd(&dst[s*256], gc * (v - A2s[s]) + bc * Zs[s]);
    }
    if (tid < 8) atomicAdd(&Zacc[b*8 + tid], Zs[tid]);
  }
}

extern "C" void kernel_launch(void* const* d_in, const int* in_sizes, int n_in,
                              void* d_out, int out_size, void* d_ws, size_t ws_size,
                              hipStream_t stream){
  const float* emb   = (const float*)d_in[0];
  const float* noise = (const float*)d_in[1];
  const float* smu   = (const float*)d_in[2];
  const float* slsig = (const float*)d_in[3];
  const float* Wk    = (const float*)d_in[4];
  const float* Wq    = (const float*)d_in[5];
  const float* Wv    = (const float*)d_in[6];
  const float* W_ih  = (const float*)d_in[7];
  const float* W_hh  = (const float*)d_in[8];
  const float* b_ih  = (const float*)d_in[9];
  const float* b_hh  = (const float*)d_in[10];
  const float* W1    = (const float*)d_in[11];
  const float* b1    = (const float*)d_in[12];
  const float* W2    = (const float*)d_in[13];
  const float* b2    = (const float*)d_in[14];
  const float* g_in  = (const float*)d_in[15];
  const float* be_in = (const float*)d_in[16];
  const float* g_s   = (const float*)d_in[17];
  const float* be_s  = (const float*)d_in[18];
  const float* g_ff  = (const float*)d_in[19];
  const float* be_ff = (const float*)d_in[20];

  float* ws     = (float*)d_ws;
  float* slotsA = ws;                 // 32768
  float* slotsB = ws + 32768;         // 32768
  float* qg     = ws + 65536;         // 32768
  float* gqbq   = ws + 98304;         // 256
  float* uacc   = ws + 98560;         // 32768
  float* Zacc   = ws + 131328;        // 128
  float* upd    = ws + 131456;        // 32768
  float* gh     = ws + 164224;        // 98304
  float* hbuf   = ws + 262528;        // 32768
  float* hid    = ws + 295296;        // 32768
  float* qbuf   = ws + 328064;        // 32768
  unsigned* bar = (unsigned*)(ws + 360832);   // total ~1.38 MB

  float* out_slots = (float*)d_out;
  float* out_attn  = out_slots + 32768;
  const int has_attn = (out_size >= 32768 + 16*8*4096);

  k_init<<<dim3(128), dim3(256), 0, stream>>>(noise, smu, slsig, slotsA, uacc, Zacc, bar);
  // init-mode q-gen from slotsA (1 barrier)
  k_slot<<<dim3(128), dim3(1024), 0, stream>>>(slotsA, slotsA, uacc, Zacc, Wv,
      W_ih, W_hh, b_ih, b_hh, W1, b1, W2, b2, g_ff, be_ff,
      Wq, Wk, g_s, be_s, g_in, be_in, qg, gqbq,
      upd, gh, hbuf, hid, qbuf, bar, 0u, out_slots, 0, 1);
  for (int it = 0; it < 3; ++it){
    int last = (it == 2);
    float* sin  = (it == 1) ? slotsB : slotsA;
    float* sout = (it == 1) ? slotsA : slotsB;
    k_main<<<dim3(1024), dim3(256), 0, stream>>>(emb, qg, gqbq, g_in, be_in,
        uacc, Zacc, out_attn, last && has_attn);
    k_slot<<<dim3(128), dim3(1024), 0, stream>>>(sin, sout, uacc, Zacc, Wv,
        W_ih, W_hh, b_ih, b_hh, W1, b1, W2, b2, g_ff, be_ff,
        Wq, Wk, g_s, be_s, g_in, be_in, qg, gqbq,
        upd, gh, hbuf, hid, qbuf, bar, 128u*(1u + 5u*(unsigned)it), out_slots, last, 0);
  }
}

// Round 8
// 328.146 us; speedup vs baseline: 1.9336x; 1.9336x over previous
//
#include <hip/hip_runtime.h>

#define DEVI __device__ __forceinline__

constexpr float SCALE = 0.0625f;   // 256^-0.5
constexpr float LN_EPS = 1e-5f;

DEVI float dot8f(const float* __restrict__ w, const float* __restrict__ x){
  float4 a = *(const float4*)w;
  float4 b = *(const float4*)(w + 4);
  return a.x*x[0]+a.y*x[1]+a.z*x[2]+a.w*x[3]+b.x*x[4]+b.y*x[5]+b.z*x[6]+b.w*x[7];
}

// 256-thr 256x256 GEMV (round-4 proven): out[tid] = dot(W[tid][:], xv[:]).
// Caller must have xv synced. Ends with the part-reduce; caller syncs before
// reusing xv/part.
DEVI float gemv256(const float* __restrict__ W, const float* __restrict__ xv,
                   float (*part)[33], int tid){
  const int c8 = tid & 31, ep = tid >> 5;
  float xs8[8];
  #pragma unroll
  for (int j = 0; j < 8; ++j) xs8[j] = xv[c8*8 + j];
  const float* Wb = W + c8*8;
  #pragma unroll 4
  for (int ei = 0; ei < 32; ++ei){
    int e = ep*32 + ei;
    part[e][c8] = dot8f(Wb + (size_t)e*256, xs8);
  }
  __syncthreads();
  float acc = 0.f;
  #pragma unroll
  for (int p = 0; p < 32; ++p) acc += part[tid][p];
  return acc;
}

// LayerNorm over the 256 values held one-per-thread (round-5 proven).
DEVI float block_ln(float x, const float* __restrict__ g, const float* __restrict__ be,
                    float* red, int tid, int lane, int wv){
  float v1 = x, v2 = x*x;
  #pragma unroll
  for (int o = 32; o; o >>= 1){ v1 += __shfl_xor(v1,o,64); v2 += __shfl_xor(v2,o,64); }
  if (lane == 0){ red[wv] = v1; red[4+wv] = v2; }
  __syncthreads();
  float mu = (red[0]+red[1]+red[2]+red[3]) * (1.f/256.f);
  float var = (red[4]+red[5]+red[6]+red[7]) * (1.f/256.f) - mu*mu;
  float inv = rsqrtf(var + LN_EPS);
  float r = (x - mu)*inv*g[tid] + be[tid];
  __syncthreads();
  return r;
}

// ---------------- K0: slots init + zero accumulators ----------------
__global__ void k_init(const float* __restrict__ noise, const float* __restrict__ smu,
                       const float* __restrict__ slsig, float* __restrict__ slotsA,
                       float* __restrict__ uacc, float* __restrict__ Zacc){
  const int r = blockIdx.x, tid = threadIdx.x, s = r & 7;
  slotsA[r*256 + tid] = smu[s*256 + tid] + expf(slsig[s*256 + tid]) * noise[r*256 + tid];
  uacc[r*256 + tid] = 0.f;
  if (tid == 0) Zacc[r] = 0.f;
}

// ---------------- kS1: upd = (uacc@Wv[s]^T)/Z  ||  gh[g] = slots_in@W_hh[g]^T ----------------
__global__ __launch_bounds__(256) void kS1(const float* __restrict__ slots_in,
    const float* __restrict__ uacc, const float* __restrict__ Zacc,
    const float* __restrict__ Wv, const float* __restrict__ W_hh,
    float* __restrict__ upd, float* __restrict__ gh){
  __shared__ float xv[256];
  __shared__ float part[256][33];
  const int m = blockIdx.x;       // 0: Wv, 1..3: W_hh gate m-1
  const int r = blockIdx.y, tid = threadIdx.x, s = r & 7;
  const float* W   = (m == 0) ? (Wv + (size_t)s*65536) : (W_hh + (size_t)(m-1)*65536);
  const float* src = (m == 0) ? (uacc + r*256) : (slots_in + r*256);
  xv[tid] = src[tid];
  __syncthreads();
  float acc = gemv256(W, xv, part, tid);
  if (m == 0) upd[r*256 + tid] = acc * (1.f / Zacc[r]);
  else        gh[((m-1)*128 + r)*256 + tid] = acc;
}

// ---------------- kS2: gi[g] = upd@W_ih[g]^T + b_ih[g]; re-zero uacc/Zacc ----------------
__global__ __launch_bounds__(256) void kS2(const float* __restrict__ upd,
    const float* __restrict__ W_ih, const float* __restrict__ b_ih,
    float* __restrict__ gi, float* __restrict__ uacc, float* __restrict__ Zacc){
  __shared__ float xv[256];
  __shared__ float part[256][33];
  const int g = blockIdx.x, r = blockIdx.y, tid = threadIdx.x;
  xv[tid] = upd[r*256 + tid];
  if (g == 0) uacc[r*256 + tid] = 0.f;
  if (g == 1 && tid == 0) Zacc[r] = 0.f;
  __syncthreads();
  float acc = gemv256(W_ih + (size_t)g*65536, xv, part, tid);
  gi[(g*128 + r)*256 + tid] = acc + b_ih[g*256 + tid];
}

// ---------------- kS3: GRU gates -> h; hbuf; LN_ff; hid = relu(LN@W1^T + b1) ----------------
__global__ __launch_bounds__(256) void kS3(const float* __restrict__ slots_in,
    const float* __restrict__ gi, const float* __restrict__ gh,
    const float* __restrict__ b_hh,
    const float* __restrict__ g_ff, const float* __restrict__ be_ff,
    const float* __restrict__ W1, const float* __restrict__ b1,
    float* __restrict__ hbuf, float* __restrict__ hid){
  __shared__ float xv[256];
  __shared__ float part[256][33];
  __shared__ float red[8];
  const int r = blockIdx.x, tid = threadIdx.x;
  const int lane = tid & 63, wv = tid >> 6;
  float i_r = gi[(0*128 + r)*256 + tid];
  float i_z = gi[(1*128 + r)*256 + tid];
  float i_n = gi[(2*128 + r)*256 + tid];
  float h_r = gh[(0*128 + r)*256 + tid] + b_hh[tid];
  float h_z = gh[(1*128 + r)*256 + tid] + b_hh[256 + tid];
  float h_n = gh[(2*128 + r)*256 + tid] + b_hh[512 + tid];
  float hp = slots_in[r*256 + tid];
  float rg = 1.f/(1.f + expf(-(i_r + h_r)));
  float zg = 1.f/(1.f + expf(-(i_z + h_z)));
  float ng = tanhf(i_n + rg*h_n);
  float h = (1.f - zg)*ng + zg*hp;
  hbuf[r*256 + tid] = h;
  float lnh = block_ln(h, g_ff, be_ff, red, tid, lane, wv);
  xv[tid] = lnh;
  __syncthreads();
  float acc = gemv256(W1, xv, part, tid);
  hid[r*256 + tid] = fmaxf(acc + b1[tid], 0.f);
}

// ---------------- kS4: slots_out = hbuf + hid@W2^T + b2 ----------------
__global__ __launch_bounds__(256) void kS4(const float* __restrict__ hid,
    const float* __restrict__ hbuf, const float* __restrict__ W2,
    const float* __restrict__ b2, float* __restrict__ slots_out,
    float* __restrict__ out_slots, int last){
  __shared__ float xv[256];
  __shared__ float part[256][33];
  const int r = blockIdx.x, tid = threadIdx.x;
  xv[tid] = hid[r*256 + tid];
  __syncthreads();
  float acc = gemv256(W2, xv, part, tid);
  float out = hbuf[r*256 + tid] + acc + b2[tid];
  slots_out[r*256 + tid] = out;
  if (last) out_slots[r*256 + tid] = out;
}

// ---------------- kS5: qbuf = LN_s(slots) @ Wq^T ----------------
__global__ __launch_bounds__(256) void kS5(const float* __restrict__ slots,
    const float* __restrict__ g_s, const float* __restrict__ be_s,
    const float* __restrict__ Wq, float* __restrict__ qbuf){
  __shared__ float xv[256];
  __shared__ float part[256][33];
  __shared__ float red[8];
  const int r = blockIdx.x, tid = threadIdx.x;
  const int lane = tid & 63, wv = tid >> 6;
  float x = slots[r*256 + tid];
  float sn = block_ln(x, g_s, be_s, red, tid, lane, wv);
  xv[tid] = sn;
  __syncthreads();
  qbuf[r*256 + tid] = gemv256(Wq, xv, part, tid);
}

// ---------------- kS6: qk = qbuf @ Wk[s]; qg = qk*g_in*SCALE; Gq/Bq ----------------
__global__ __launch_bounds__(256) void kS6(const float* __restrict__ qbuf,
    const float* __restrict__ Wk,
    const float* __restrict__ g_in, const float* __restrict__ be_in,
    float* __restrict__ qg, float* __restrict__ gqbq){
  __shared__ float xv[256];
  __shared__ float partK[8][256];
  __shared__ float red[8];
  const int r = blockIdx.x, tid = threadIdx.x, s = r & 7;
  const int lane = tid & 63, wv = tid >> 6;
  xv[tid] = qbuf[r*256 + tid];
  __syncthreads();
  const int c8 = tid & 31, ep = tid >> 5;
  float acc8[8];
  #pragma unroll
  for (int j = 0; j < 8; ++j) acc8[j] = 0.f;
  const float* Wb = Wk + ((size_t)s*256)*256 + c8*8;
  #pragma unroll 4
  for (int ei = 0; ei < 32; ++ei){
    int e = ep*32 + ei;
    const float* wp = Wb + (size_t)e*256;
    float4 wa = *(const float4*)wp;
    float4 wb = *(const float4*)(wp + 4);
    float qe = xv[e];
    acc8[0] += qe*wa.x; acc8[1] += qe*wa.y; acc8[2] += qe*wa.z; acc8[3] += qe*wa.w;
    acc8[4] += qe*wb.x; acc8[5] += qe*wb.y; acc8[6] += qe*wb.z; acc8[7] += qe*wb.w;
  }
  float* pk = &partK[ep][c8*8];
  #pragma unroll
  for (int j = 0; j < 8; ++j) pk[j] = acc8[j];
  __syncthreads();
  float qk = 0.f;
  #pragma unroll
  for (int p = 0; p < 8; ++p) qk += partK[p][tid];
  float qgv = qk * g_in[tid] * SCALE;
  float bqv = qk * be_in[tid] * SCALE;
  qg[r*256 + tid] = qgv;
  float vq = qgv, vb = bqv;
  #pragma unroll
  for (int o = 32; o; o >>= 1){ vq += __shfl_xor(vq,o,64); vb += __shfl_xor(vb,o,64); }
  if (lane == 0){ red[wv] = vq; red[4+wv] = vb; }
  __syncthreads();
  if (tid == 0) gqbq[r*2+0] = red[0]+red[1]+red[2]+red[3];
  if (tid == 1) gqbq[r*2+1] = red[4]+red[5]+red[6]+red[7];
}

// ---------------- K1: fused LN + dots + softmax(slots) + weighted-emb accumulation --------
__global__ __launch_bounds__(256) void k_main(const float* __restrict__ emb,
    const float* __restrict__ qg, const float* __restrict__ gqbq,
    const float* __restrict__ g_in, const float* __restrict__ be_in,
    float* __restrict__ uacc, float* __restrict__ Zacc,
    float* __restrict__ out_attn, int write_attn){
  __shared__ float U[8192];                    // 32 KB union
  float* const qgL = U;                        // [2048] phase 1 (bank-swizzled)
  float* const avL = U + 2048;                 // [512]  phase 1
  float4* const Sp4 = (float4*)U;              // [2048] phase 2 partials
  __shared__ float aL[512];
  __shared__ float red2[2][8][4];
  __shared__ float Zs[8], A2s[8], GqL[8], BqL[8];

  const int tid = threadIdx.x, lane = tid & 63, wv = tid >> 6;
  const int blk = blockIdx.x, b = blk >> 6, tile = blk & 63;
  const int n0 = tile * 64;

  { // stage queries with per-qq rotation so the 8 qq-chunks hit distinct banks
    const float4* src = (const float4*)(qg + (size_t)b * 2048);
    float4* dst = (float4*)qgL;
    #pragma unroll
    for (int k = 0; k < 2; ++k){
      int w = tid + k*256;                 // 0..511
      int s = w >> 6, f = w & 63, qq = f >> 3, j = f & 7;
      dst[s*64 + qq*8 + ((j + qq) & 7)] = src[w];
    }
  }
  if (tid < 8){
    GqL[tid] = gqbq[(b*8 + tid)*2 + 0];
    BqL[tid] = gqbq[(b*8 + tid)*2 + 1];
  }
  __syncthreads();

  const int qq = tid & 7;   // 32-col chunk
  float zsum[8], z2sum[8];
  #pragma unroll
  for (int s = 0; s < 8; ++s){ zsum[s] = 0.f; z2sum[s] = 0.f; }

  #pragma unroll
  for (int pass = 0; pass < 2; ++pass){
    const int t = pass*32 + (tid >> 3);   // token 0..63
    const float4* xrow = (const float4*)(emb + ((size_t)(b*4096 + n0 + t))*256 + qq*32);
    float4 xv4[8];
    #pragma unroll
    for (int j = 0; j < 8; ++j) xv4[j] = xrow[j];
    float s1 = 0.f, s2 = 0.f, acc[8];
    #pragma unroll
    for (int s = 0; s < 8; ++s) acc[s] = 0.f;
    #pragma unroll
    for (int j = 0; j < 8; ++j){
      float4 u = xv4[j];
      s1 += (u.x+u.y)+(u.z+u.w);
      s2 += u.x*u.x+u.y*u.y+u.z*u.z+u.w*u.w;
      const float* qb = qgL + qq*32 + ((j + qq) & 7)*4;
      #pragma unroll
      for (int s = 0; s < 8; ++s){
        float4 q0 = *(const float4*)(qb + s*256);
        acc[s] += u.x*q0.x + u.y*q0.y + u.z*q0.z + u.w*q0.w;
      }
    }
    #pragma unroll
    for (int o = 1; o <= 4; o <<= 1){
      s1 += __shfl_xor(s1,o,64); s2 += __shfl_xor(s2,o,64);
      #pragma unroll
      for (int s = 0; s < 8; ++s) acc[s] += __shfl_xor(acc[s],o,64);
    }
    float mu = s1 * (1.f/256.f);
    float var = s2 * (1.f/256.f) - mu*mu;
    float inv = rsqrtf(var + LN_EPS);
    float dv[8], mx = -1e30f;
    #pragma unroll
    for (int s = 0; s < 8; ++s){
      dv[s] = inv * (acc[s] - mu * GqL[s]) + BqL[s];
      mx = fmaxf(mx, dv[s]);
    }
    float den = 0.f;
    #pragma unroll
    for (int s = 0; s < 8; ++s){ dv[s] = expf(dv[s] - mx); den += dv[s]; }
    float rden = 1.f / den;
    #pragma unroll
    for (int s = 0; s < 8; ++s){
      float at = dv[s] * rden;       // attn (softmax over slots)
      float av = at * inv;           // attn * inv (LN folded)
      if (qq == 0){ avL[s*64 + t] = at; aL[s*64 + t] = av; }
      zsum[s] += at;                 // deferred reduction (single butterfly below)
      z2sum[s] += av * mu;
    }
  }
  // one butterfly for Z/A2 instead of per-pass (each token counted by 8 lanes)
  #pragma unroll
  for (int s = 0; s < 8; ++s){
    #pragma unroll
    for (int o = 32; o; o >>= 1){
      zsum[s] += __shfl_xor(zsum[s], o, 64);
      z2sum[s] += __shfl_xor(z2sum[s], o, 64);
    }
  }
  if (lane == 0){
    #pragma unroll
    for (int s = 0; s < 8; ++s){ red2[0][s][wv] = zsum[s]*0.125f; red2[1][s][wv] = z2sum[s]*0.125f; }
  }
  __syncthreads();
  if (tid < 8){
    Zs[tid]  = red2[0][tid][0]+red2[0][tid][1]+red2[0][tid][2]+red2[0][tid][3];
    A2s[tid] = red2[1][tid][0]+red2[1][tid][1]+red2[1][tid][2]+red2[1][tid][3];
  }
  if (write_attn){
    int s = tid >> 5, tk = tid & 31;
    #pragma unroll
    for (int p = 0; p < 2; ++p)
      out_attn[((size_t)(b*8 + s))*4096 + n0 + p*32 + tk] = avL[s*64 + p*32 + tk];
  }
  __syncthreads();                   // avL/qgL dead past here; Sp4 takes over U
  { // phase 2: coalesced f4 token-weighted accumulation
    const int r4 = tid >> 6, cq = tid & 63;
    float4 S1[8];
    #pragma unroll
    for (int s = 0; s < 8; ++s) S1[s] = make_float4(0.f,0.f,0.f,0.f);
    const float4* xbase = (const float4*)(emb + ((size_t)(b*4096 + n0))*256) + cq;
    #pragma unroll 4
    for (int i = 0; i < 16; ++i){
      int t = r4 + i*4;
      float4 x4 = xbase[t*64];
      #pragma unroll
      for (int s = 0; s < 8; ++s){
        float a = aL[s*64 + t];   // wave-uniform broadcast
        S1[s].x += a*x4.x; S1[s].y += a*x4.y; S1[s].z += a*x4.z; S1[s].w += a*x4.w;
      }
    }
    #pragma unroll
    for (int s = 0; s < 8; ++s) Sp4[(r4*8 + s)*64 + cq] = S1[s];
  }
  __syncthreads();
  { // final: sum 4 wave-partials per (s,c), atomically accumulate (s staggered)
    const int c = tid;
    const float* Sp = (const float*)Sp4;
    float gc = g_in[c], bc = be_in[c];
    float* dst = uacc + ((size_t)b*8)*256 + c;
    #pragma unroll
    for (int si = 0; si < 8; ++si){
      int s = (si + blk) & 7;
      float v = Sp[(0*8+s)*256 + c] + Sp[(1*8+s)*256 + c]
              + Sp[(2*8+s)*256 + c] + Sp[(3*8+s)*256 + c];
      atomicAdd(&dst[s*256], gc * (v - A2s[s]) + bc * Zs[s]);
    }
    if (tid < 8) atomicAdd(&Zacc[b*8 + tid], Zs[tid]);
  }
}

extern "C" void kernel_launch(void* const* d_in, const int* in_sizes, int n_in,
                              void* d_out, int out_size, void* d_ws, size_t ws_size,
                              hipStream_t stream){
  const float* emb   = (const float*)d_in[0];
  const float* noise = (const float*)d_in[1];
  const float* smu   = (const float*)d_in[2];
  const float* slsig = (const float*)d_in[3];
  const float* Wk    = (const float*)d_in[4];
  const float* Wq    = (const float*)d_in[5];
  const float* Wv    = (const float*)d_in[6];
  const float* W_ih  = (const float*)d_in[7];
  const float* W_hh  = (const float*)d_in[8];
  const float* b_ih  = (const float*)d_in[9];
  const float* b_hh  = (const float*)d_in[10];
  const float* W1    = (const float*)d_in[11];
  const float* b1    = (const float*)d_in[12];
  const float* W2    = (const float*)d_in[13];
  const float* b2    = (const float*)d_in[14];
  const float* g_in  = (const float*)d_in[15];
  const float* be_in = (const float*)d_in[16];
  const float* g_s   = (const float*)d_in[17];
  const float* be_s  = (const float*)d_in[18];
  const float* g_ff  = (const float*)d_in[19];
  const float* be_ff = (const float*)d_in[20];

  float* ws     = (float*)d_ws;
  float* slotsA = ws;                 // 32768
  float* slotsB = ws + 32768;         // 32768
  float* qg     = ws + 65536;         // 32768
  float* gqbq   = ws + 98304;         // 256
  float* uacc   = ws + 98560;         // 32768
  float* Zacc   = ws + 131328;        // 128
  float* upd    = ws + 131456;        // 32768
  float* gh     = ws + 164224;        // 98304
  float* gi     = ws + 262528;        // 98304
  float* hbuf   = ws + 360832;        // 32768
  float* hid    = ws + 393600;        // 32768
  float* qbuf   = ws + 426368;        // 32768  (total ~1.84 MB)

  float* out_slots = (float*)d_out;
  float* out_attn  = out_slots + 32768;
  const int has_attn = (out_size >= 32768 + 16*8*4096);

  k_init<<<dim3(128), dim3(256), 0, stream>>>(noise, smu, slsig, slotsA, uacc, Zacc);
  kS5<<<dim3(128), dim3(256), 0, stream>>>(slotsA, g_s, be_s, Wq, qbuf);
  kS6<<<dim3(128), dim3(256), 0, stream>>>(qbuf, Wk, g_in, be_in, qg, gqbq);
  for (int it = 0; it < 3; ++it){
    int last = (it == 2);
    float* sin  = (it == 1) ? slotsB : slotsA;
    float* sout = (it == 1) ? slotsA : slotsB;
    k_main<<<dim3(1024), dim3(256), 0, stream>>>(emb, qg, gqbq, g_in, be_in,
        uacc, Zacc, out_attn, last && has_attn);
    kS1<<<dim3(4,128), dim3(256), 0, stream>>>(sin, uacc, Zacc, Wv, W_hh, upd, gh);
    kS2<<<dim3(3,128), dim3(256), 0, stream>>>(upd, W_ih, b_ih, gi, uacc, Zacc);
    kS3<<<dim3(128), dim3(256), 0, stream>>>(sin, gi, gh, b_hh, g_ff, be_ff, W1, b1, hbuf, hid);
    kS4<<<dim3(128), dim3(256), 0, stream>>>(hid, hbuf, W2, b2, sout, out_slots, last);
    if (!last){
      kS5<<<dim3(128), dim3(256), 0, stream>>>(sout, g_s, be_s, Wq, qbuf);
      kS6<<<dim3(128), dim3(256), 0, stream>>>(qbuf, Wk, g_in, be_in, qg, gqbq);
    }
  }
}